// Round 6
// baseline (1278.348 us; speedup 1.0000x reference)
//
#include <hip/hip_runtime.h>
#include <hip/hip_bf16.h>

typedef unsigned short ushort;
typedef unsigned int uint;
typedef short bf16x8 __attribute__((ext_vector_type(8)));
typedef ushort us8 __attribute__((ext_vector_type(8)));
typedef float f32x4 __attribute__((ext_vector_type(4)));

#define HW 4096

__device__ __forceinline__ float us2f(ushort u) { return __uint_as_float(((uint)u) << 16); }
__device__ __forceinline__ ushort f2us(float f) {
  uint u = __float_as_uint(f);
  u += 0x7FFFu + ((u >> 16) & 1u);
  return (ushort)(u >> 16);
}
__device__ __forceinline__ void split_bf16(float f, ushort& hi, ushort& lo) {
  hi = f2us(f);
  lo = f2us(f - us2f(hi));
}

// ---------------------------------------------------------------------------
// x [8][256][4096] fp32 -> xt [8][4096][256] fp32. Plain LDS tile transpose.
// ---------------------------------------------------------------------------
__global__ __launch_bounds__(256) void transpose_x_kernel(
    const float* __restrict__ x, float* __restrict__ xt) {
  __shared__ float sT[64][65];
  const int b = blockIdx.y;
  const int n0 = blockIdx.x * 64;
  const int tid = threadIdx.x;
  for (int cb = 0; cb < 256; cb += 64) {
    if (cb) __syncthreads();
    {
      int cl = tid >> 4;           // 0..15
      int n4 = (tid & 15) * 4;
#pragma unroll
      for (int it = 0; it < 4; ++it) {
        int c = cl + it * 16;
        float4 v = *(const float4*)&x[((size_t)b * 256 + cb + c) * HW + n0 + n4];
        sT[c][n4] = v.x; sT[c][n4 + 1] = v.y; sT[c][n4 + 2] = v.z; sT[c][n4 + 3] = v.w;
      }
    }
    __syncthreads();
    {
      int nl = tid >> 4;
      int c4 = (tid & 15) * 4;
#pragma unroll
      for (int it = 0; it < 4; ++it) {
        int n = nl + it * 16;
        float4 v = { sT[c4][n], sT[c4 + 1][n], sT[c4 + 2][n], sT[c4 + 3][n] };
        *(float4*)&xt[((size_t)b * HW + n0 + n) * 256 + cb + c4] = v;
      }
    }
  }
}

// ---------------------------------------------------------------------------
// DIAGNOSTIC round: plain VALU GEMM1 (replaces the MFMA+patch-epilogue kernel).
// qkv_t[b][n][768] = xt[b][n][:] . w_qkv[o][:]   fp32 accum, bf16 store.
// Block: 32 pixels; thread (p = tid&31, j = tid>>5) handles o in [96j, 96j+96).
// ---------------------------------------------------------------------------
__global__ __launch_bounds__(256) void gemm1_valu_kernel(
    const float* __restrict__ Xt,   // [8][4096][256] fp32
    const float* __restrict__ Wm,   // [768][256] fp32
    ushort* __restrict__ OutT) {    // [8][4096][768] bf16
  __shared__ float sX[32][257];     // +1 pad: bank = (p + c) & 31, conflict-free
  const int b = blockIdx.y;
  const int n0 = blockIdx.x * 32;
  const int tid = threadIdx.x;
  {
    int row = tid >> 3, c0 = (tid & 7) * 32;
    const float* src = &Xt[((size_t)b * HW + n0 + row) * 256 + c0];
#pragma unroll
    for (int it = 0; it < 8; ++it) {
      float4 v = *(const float4*)&src[it * 4];
      sX[row][c0 + it * 4 + 0] = v.x;
      sX[row][c0 + it * 4 + 1] = v.y;
      sX[row][c0 + it * 4 + 2] = v.z;
      sX[row][c0 + it * 4 + 3] = v.w;
    }
  }
  __syncthreads();
  const int p = tid & 31, j = tid >> 5;
  for (int oo = 0; oo < 96; ++oo) {
    int o = j * 96 + oo;
    const float* wrow = &Wm[(size_t)o * 256];
    float a = 0.f;
#pragma unroll 4
    for (int c = 0; c < 256; c += 4) {
      float4 wv = *(const float4*)&wrow[c];
      a = fmaf(sX[p][c + 0], wv.x, a);
      a = fmaf(sX[p][c + 1], wv.y, a);
      a = fmaf(sX[p][c + 2], wv.z, a);
      a = fmaf(sX[p][c + 3], wv.w, a);
    }
    OutT[((size_t)b * HW + n0 + p) * 768 + o] = f2us(a);
  }
}

// ---------------------------------------------------------------------------
// MFMA GEMM2: out[b][256][4096] fp32 = BN(att_t @ w_proj^T).
// W split hi/lo, X = att bf16. BK=32.  (unchanged from round 5)
// ---------------------------------------------------------------------------
__global__ __launch_bounds__(256) void mfma_gemm2_kernel(
    const ushort* __restrict__ Xt,  // [8][4096][512] bf16
    const float* __restrict__ Wm,   // [256][512] fp32
    float* __restrict__ Out,        // [8][256][4096] fp32
    const float* __restrict__ bng, const float* __restrict__ bnb,
    const float* __restrict__ bnm, const float* __restrict__ bnv) {
  constexpr int M = 256, K = 512;
  __shared__ __align__(16) char smem[30720];
  ushort(*sWh)[40] = (ushort(*)[40])smem;
  ushort(*sWl)[40] = (ushort(*)[40])(smem + 10240);
  ushort(*sX)[40] = (ushort(*)[40])(smem + 20480);
  const int b = blockIdx.z;
  const int m0 = blockIdx.y * 128;
  const int n0 = blockIdx.x * 128;
  const int tid = threadIdx.x;
  const int lane = tid & 63, wave = tid >> 6;
  const int wm = wave >> 1, wn = wave & 1;
  const int quad = lane >> 4, l16 = lane & 15;
  f32x4 acc[4][4] = {};
  const ushort* Xb = Xt + ((size_t)b * HW + n0) * K;

  for (int k0 = 0; k0 < K; k0 += 32) {
    {
      int k4 = (tid & 7) * 4;
      int mrow = tid >> 3;  // 0..31
#pragma unroll
      for (int it = 0; it < 4; ++it) {
        int m = it * 32 + mrow;
        float4 r = *(const float4*)&Wm[(size_t)(m0 + m) * K + k0 + k4];
        ushort4 h, l;
        split_bf16(r.x, h.x, l.x);
        split_bf16(r.y, h.y, l.y);
        split_bf16(r.z, h.z, l.z);
        split_bf16(r.w, h.w, l.w);
        *(ushort4*)&sWh[m][k4] = h;
        *(ushort4*)&sWl[m][k4] = l;
      }
      int k8 = (tid & 3) * 8;
      int nrow = tid >> 2;  // 0..63
#pragma unroll
      for (int it = 0; it < 2; ++it) {
        int n = it * 64 + nrow;
        *(uint4*)&sX[n][k8] = *(const uint4*)&Xb[(size_t)n * K + k0 + k8];
      }
    }
    __syncthreads();
    bf16x8 afh[4], afl[4], bfr[4];
#pragma unroll
    for (int i = 0; i < 4; ++i) {
      afh[i] = *(const bf16x8*)&sWh[wm * 64 + i * 16 + l16][quad * 8];
      afl[i] = *(const bf16x8*)&sWl[wm * 64 + i * 16 + l16][quad * 8];
    }
#pragma unroll
    for (int j = 0; j < 4; ++j)
      bfr[j] = *(const bf16x8*)&sX[wn * 64 + j * 16 + l16][quad * 8];
#pragma unroll
    for (int i = 0; i < 4; ++i)
#pragma unroll
      for (int j = 0; j < 4; ++j) {
        acc[i][j] = __builtin_amdgcn_mfma_f32_16x16x32_bf16(afh[i], bfr[j], acc[i][j], 0, 0, 0);
        acc[i][j] = __builtin_amdgcn_mfma_f32_16x16x32_bf16(afl[i], bfr[j], acc[i][j], 0, 0, 0);
      }
    __syncthreads();
  }
#pragma unroll
  for (int mi = 0; mi < 4; ++mi) {
#pragma unroll
    for (int r = 0; r < 4; ++r) {
      int o = m0 + wm * 64 + mi * 16 + quad * 4 + r;
      float inv = bng[o] * rsqrtf(bnv[o] + 1e-5f);
      float shift = bnb[o] - bnm[o] * inv;
#pragma unroll
      for (int ni = 0; ni < 4; ++ni) {
        int n = n0 + wn * 64 + ni * 16 + l16;
        Out[((size_t)b * M + o) * HW + n] = acc[mi][ni][r] * inv + shift;
      }
    }
  }
}

// ---------------------------------------------------------------------------
// Depthwise 5x5 + grouped pointwise (8->8), [n][c] layouts. (unchanged)
// ---------------------------------------------------------------------------
__global__ __launch_bounds__(256) void dwpw_kernel(
    const ushort* __restrict__ qkv_t,  // [8][4096][768]
    const float* __restrict__ wdw,     // [768][25]
    const float* __restrict__ wpw,     // [96][8][8]
    ushort* __restrict__ pw_t) {       // [8][4096][768]
  __shared__ float sT[8][12][68];
  __shared__ float sWd[8][25];
  __shared__ float sWp[8][8];
  const int b = blockIdx.z, g = blockIdx.y, h0 = blockIdx.x * 8;
  const int tid = threadIdx.x;
  for (int i = tid; i < 200; i += 256)
    sWd[i / 25][i % 25] = wdw[(g * 8 + i / 25) * 25 + i % 25];
  if (tid < 64) sWp[tid >> 3][tid & 7] = wpw[g * 64 + tid];
  for (int pos = tid; pos < 816; pos += 256) {
    int rr = pos / 68, cc = pos % 68;
    int h = h0 + rr - 2, w = cc - 2;
    float v[8] = {};
    if (h >= 0 && h < 64 && w >= 0 && w < 64) {
      us8 u = *(const us8*)&qkv_t[((size_t)b * HW + h * 64 + w) * 768 + g * 8];
#pragma unroll
      for (int j = 0; j < 8; ++j) v[j] = us2f(u[j]);
    }
#pragma unroll
    for (int j = 0; j < 8; ++j) sT[j][rr][cc] = v[j];
  }
  __syncthreads();
  const int tw = tid & 63, th = tid >> 6;
#pragma unroll
  for (int rep = 0; rep < 2; ++rep) {
    int rl = th + rep * 4;
    float dwv[8];
#pragma unroll
    for (int ci = 0; ci < 8; ++ci) {
      float a = 0.f;
#pragma unroll
      for (int dy = 0; dy < 5; ++dy)
#pragma unroll
        for (int dx = 0; dx < 5; ++dx)
          a = fmaf(sT[ci][rl + dy][tw + dx], sWd[ci][dy * 5 + dx], a);
      dwv[ci] = a;
    }
    us8 outv;
#pragma unroll
    for (int o = 0; o < 8; ++o) {
      float a = 0.f;
#pragma unroll
      for (int i = 0; i < 8; ++i) a = fmaf(sWp[o][i], dwv[i], a);
      outv[o] = f2us(a);
    }
    *(us8*)&pw_t[((size_t)b * HW + (h0 + rl) * 64 + tw) * 768 + g * 8] = outv;
  }
}

// ---------------------------------------------------------------------------
// ReLU linear attention, [n][c] layouts. One block per (b, head). (unchanged)
// ---------------------------------------------------------------------------
__global__ __launch_bounds__(256) void attn_kernel(
    const ushort* __restrict__ qkv_t, const ushort* __restrict__ pw_t,
    ushort* __restrict__ att_t) {  // [8][4096][512]
  const int bh = blockIdx.x;
  const int b = bh >> 6, h = bh & 63;
  const ushort* src = (h < 32) ? qkv_t + (size_t)b * HW * 768 + 24 * h
                               : pw_t + (size_t)b * HW * 768 + 24 * (h - 32);
  const int tid = threadIdx.x;
  float kv[72] = {};  // kv[d*9+e]
  for (int n = tid; n < HW; n += 256) {
    const ushort* p = src + (size_t)n * 768;
    us8 ku = *(const us8*)(p + 8);
    us8 vu = *(const us8*)(p + 16);
    float kd[8], ve[8];
#pragma unroll
    for (int d = 0; d < 8; ++d) kd[d] = fmaxf(us2f(ku[d]), 0.f);
#pragma unroll
    for (int e = 0; e < 8; ++e) ve[e] = us2f(vu[e]);
#pragma unroll
    for (int d = 0; d < 8; ++d) {
#pragma unroll
      for (int e = 0; e < 8; ++e) kv[d * 9 + e] = fmaf(kd[d], ve[e], kv[d * 9 + e]);
      kv[d * 9 + 8] += kd[d];
    }
  }
  __shared__ float sRed[4][72];
  __shared__ float sKV[72];
  const int lane = tid & 63, wave = tid >> 6;
#pragma unroll
  for (int t = 0; t < 72; ++t) {
    float v = kv[t];
    v += __shfl_down(v, 32);
    v += __shfl_down(v, 16);
    v += __shfl_down(v, 8);
    v += __shfl_down(v, 4);
    v += __shfl_down(v, 2);
    v += __shfl_down(v, 1);
    if (lane == 0) sRed[wave][t] = v;
  }
  __syncthreads();
  if (tid < 72) sKV[tid] = sRed[0][tid] + sRed[1][tid] + sRed[2][tid] + sRed[3][tid];
  __syncthreads();
  float kvf[72];
#pragma unroll
  for (int t = 0; t < 72; ++t) kvf[t] = sKV[t];
  for (int n = tid; n < HW; n += 256) {
    const ushort* p = src + (size_t)n * 768;
    us8 qu = *(const us8*)p;
    float qd[8];
#pragma unroll
    for (int d = 0; d < 8; ++d) qd[d] = fmaxf(us2f(qu[d]), 0.f);
    float o[9] = {};
#pragma unroll
    for (int d = 0; d < 8; ++d)
#pragma unroll
      for (int e = 0; e < 9; ++e) o[e] = fmaf(qd[d], kvf[d * 9 + e], o[e]);
    float rinv = 1.0f / (o[8] + 1e-15f);
    us8 ov;
#pragma unroll
    for (int e = 0; e < 8; ++e) ov[e] = f2us(o[e] * rinv);
    *(us8*)&att_t[((size_t)b * HW + n) * 512 + h * 8] = ov;
  }
}

// ---------------------------------------------------------------------------
extern "C" void kernel_launch(void* const* d_in, const int* in_sizes, int n_in,
                              void* d_out, int out_size, void* d_ws, size_t ws_size,
                              hipStream_t stream) {
  const float* x = (const float*)d_in[0];
  const float* w_qkv = (const float*)d_in[1];
  const float* w_dw = (const float*)d_in[2];
  const float* w_pw = (const float*)d_in[3];
  const float* w_proj = (const float*)d_in[4];
  const float* bng = (const float*)d_in[5];
  const float* bnb = (const float*)d_in[6];
  const float* bnm = (const float*)d_in[7];
  const float* bnv = (const float*)d_in[8];
  float* out = (float*)d_out;

  char* ws = (char*)d_ws;
  ushort* qkv_t = (ushort*)ws;                 // [0, 48 MiB)
  ushort* pw_t = (ushort*)(ws + 50331648);     // [48, 96)
  ushort* att_t = (ushort*)(ws + 100663296);   // [96, 128)
  float* xt = (float*)(ws + 67108864);         // [64, 96) fp32 — dead after GEMM1

  // 0) transpose x -> xt [b][n][256] fp32
  transpose_x_kernel<<<dim3(64, 8), 256, 0, stream>>>(x, xt);
  // 1) qkv_t[b][n][768] = xt @ w_qkv^T  (VALU diagnostic GEMM)
  gemm1_valu_kernel<<<dim3(128, 8), 256, 0, stream>>>(xt, w_qkv, qkv_t);
  // 2) pw_t = grouped_pointwise(depthwise5x5(qkv_t))
  dwpw_kernel<<<dim3(8, 96, 8), 256, 0, stream>>>(qkv_t, w_dw, w_pw, pw_t);
  // 3) att_t[b][n][512] = relu_linear_attention(concat(qkv_t, pw_t))
  attn_kernel<<<dim3(512), 256, 0, stream>>>(qkv_t, pw_t, att_t);
  // 4) out[b][256][4096] = BN(att_t @ w_proj^T)  (MFMA, W split)
  mfma_gemm2_kernel<<<dim3(32, 2, 8), 256, 0, stream>>>(
      att_t, w_proj, out, bng, bnb, bnm, bnv);
}